// Round 1
// baseline (452.094 us; speedup 1.0000x reference)
//
#include <hip/hip_runtime.h>
#include <type_traits>

typedef __attribute__((ext_vector_type(8))) short short8;
typedef __attribute__((ext_vector_type(4))) float f32x4;
typedef unsigned short u16;
typedef unsigned int   u32;

// B=4, S=2048, D=1024, H=16, DK=64, M = B*S = 8192

static __device__ __forceinline__ u16 f2b(float f) {
  u32 u = __builtin_bit_cast(u32, f);
  u = (u + 0x7fffu + ((u >> 16) & 1u)) >> 16;
  return (u16)u;
}
static __device__ __forceinline__ float b2f(u16 h) {
  return __builtin_bit_cast(float, ((u32)h) << 16);
}

// ---------------- fp32 -> bf16 convert ----------------
__global__ __launch_bounds__(256) void cvt_kernel(const float* __restrict__ in,
                                                  u16* __restrict__ out, int n) {
  int i = (blockIdx.x * 256 + threadIdx.x) * 4;
  if (i >= n) return;
  float4 v = *(const float4*)(in + i);
  union { u16 us[4]; unsigned long long ull; } o;
  o.us[0] = f2b(v.x); o.us[1] = f2b(v.y); o.us[2] = f2b(v.z); o.us[3] = f2b(v.w);
  *(unsigned long long*)(out + i) = o.ull;
}

// ---------------- GEMM: C[m,n] = sum_k A[m,k]*B[n,k]  (B^T form) ----------
// A: M x 1024 bf16, B: 1024 x 1024 bf16 (row-major, rows are output cols)
// 128x128 tile, BK=32, 256 threads (4 waves, 2x2 wave grid, 64x64 per wave)
template <typename OT>
static __device__ __forceinline__ void gemm_body(const u16* __restrict__ A,
                                                 const u16* __restrict__ B,
                                                 OT* __restrict__ C,
                                                 int m0, int n0) {
  __shared__ u16 As[128][40];  // +8 pad, 16B-aligned rows
  __shared__ u16 Bs[128][40];

  const int tid  = threadIdx.x;
  const int lane = tid & 63;
  const int wv   = tid >> 6;
  const int quad = lane >> 4;
  const int cc   = lane & 15;
  const int wr   = wv >> 1;   // wave row (0..1)
  const int wc   = wv & 1;    // wave col (0..1)

  f32x4 acc[4][4];
#pragma unroll
  for (int i = 0; i < 4; i++)
#pragma unroll
    for (int j = 0; j < 4; j++) acc[i][j] = (f32x4){0.f, 0.f, 0.f, 0.f};

  const int srow  = tid >> 1;          // 0..127
  const int shalf = (tid & 1) * 16;    // 0 or 16
  const u16* Ap = A + (size_t)(m0 + srow) * 1024 + shalf;
  const u16* Bp = B + (size_t)(n0 + srow) * 1024 + shalf;

  uint4 a0 = *(const uint4*)(Ap);
  uint4 a1 = *(const uint4*)(Ap + 8);
  uint4 b0 = *(const uint4*)(Bp);
  uint4 b1 = *(const uint4*)(Bp + 8);

  for (int k0 = 0; k0 < 1024; k0 += 32) {
    __syncthreads();
    *(uint4*)&As[srow][shalf]     = a0;
    *(uint4*)&As[srow][shalf + 8] = a1;
    *(uint4*)&Bs[srow][shalf]     = b0;
    *(uint4*)&Bs[srow][shalf + 8] = b1;
    __syncthreads();

    if (k0 + 32 < 1024) {  // prefetch next K-tile, overlaps with MFMA below
      a0 = *(const uint4*)(Ap + k0 + 32);
      a1 = *(const uint4*)(Ap + k0 + 40);
      b0 = *(const uint4*)(Bp + k0 + 32);
      b1 = *(const uint4*)(Bp + k0 + 40);
    }

    short8 af[4], bf[4];
#pragma unroll
    for (int mt = 0; mt < 4; mt++)
      af[mt] = *(const short8*)&As[wr * 64 + mt * 16 + cc][quad * 8];
#pragma unroll
    for (int nt = 0; nt < 4; nt++)
      bf[nt] = *(const short8*)&Bs[wc * 64 + nt * 16 + cc][quad * 8];

#pragma unroll
    for (int mt = 0; mt < 4; mt++)
#pragma unroll
      for (int nt = 0; nt < 4; nt++)
        acc[mt][nt] = __builtin_amdgcn_mfma_f32_16x16x32_bf16(af[mt], bf[nt], acc[mt][nt], 0, 0, 0);
  }

  // epilogue: C layout col=lane&15, row=quad*4+reg
#pragma unroll
  for (int mt = 0; mt < 4; mt++)
#pragma unroll
    for (int nt = 0; nt < 4; nt++)
#pragma unroll
      for (int r = 0; r < 4; r++) {
        int row = m0 + wr * 64 + mt * 16 + quad * 4 + r;
        int col = n0 + wc * 64 + nt * 16 + cc;
        if constexpr (std::is_same_v<OT, float>)
          C[(size_t)row * 1024 + col] = acc[mt][nt][r];
        else
          C[(size_t)row * 1024 + col] = f2b(acc[mt][nt][r]);
      }
}

__global__ __launch_bounds__(256) void gemm_qkv(const u16* __restrict__ A,
                                                const u16* __restrict__ Bq,
                                                const u16* __restrict__ Bk,
                                                const u16* __restrict__ Bv,
                                                u16* __restrict__ Q,
                                                u16* __restrict__ K,
                                                u16* __restrict__ V) {
  int sel = blockIdx.x >> 3;  // 8 n-blocks per matrix
  const u16* B = (sel == 0) ? Bq : (sel == 1) ? Bk : Bv;
  u16* C = (sel == 0) ? Q : (sel == 1) ? K : V;
  gemm_body<u16>(A, B, C, blockIdx.y * 128, (blockIdx.x & 7) * 128);
}

__global__ __launch_bounds__(256) void gemm_out(const u16* __restrict__ A,
                                                const u16* __restrict__ B,
                                                float* __restrict__ C) {
  gemm_body<float>(A, B, C, blockIdx.y * 128, blockIdx.x * 128);
}

// ---------------- RoPE on Q and K (in place, bf16) ----------------
__global__ __launch_bounds__(256) void rope_kernel(u16* __restrict__ Q,
                                                   u16* __restrict__ K,
                                                   const int* __restrict__ pos) {
  u16* T = blockIdx.y ? K : Q;
  int idx = blockIdx.x * 256 + threadIdx.x;  // pair index: 8192*512 total
  int row = idx >> 9;                        // 0..8191
  int p   = idx & 511;
  int i   = p & 31;                          // freq index within head
  int col = (p >> 5) * 64 + 2 * i;
  int s   = row & 2047;
  float ps  = (float)pos[s];
  // inv_freq = 10000^(-i/32) = exp2(-i * log2(10000)/32)
  float inv = exp2f(-(float)i * 0.41524101186092033f);
  float ang = ps * inv;
  float sn, cs;
  sincosf(ang, &sn, &cs);
  u32 v = *(u32*)(T + (size_t)row * 1024 + col);
  float x1 = b2f((u16)(v & 0xffffu));
  float x2 = b2f((u16)(v >> 16));
  float y1 = x1 * cs - x2 * sn;
  float y2 = x1 * sn + x2 * cs;
  *(u32*)(T + (size_t)row * 1024 + col) = (u32)f2b(y1) | ((u32)f2b(y2) << 16);
}

// ---------------- transpose V: (b,s,h,d) -> Vt[(b,h,d), s] ----------------
__global__ __launch_bounds__(256) void transpose_v(const u16* __restrict__ V,
                                                   u16* __restrict__ Vt) {
  __shared__ u16 t[64][65];
  int s0 = blockIdx.x * 64;
  int bh = blockIdx.y;
  int b = bh >> 4, h = bh & 15;
  int tid = threadIdx.x;
  int r = tid >> 2, ch = (tid & 3) * 16;
  const u16* src = V + (size_t)(b * 2048 + s0 + r) * 1024 + h * 64 + ch;
  union { uint4 v[2]; u16 us[16]; } tmp;
  tmp.v[0] = *(const uint4*)src;
  tmp.v[1] = *(const uint4*)(src + 8);
#pragma unroll
  for (int j = 0; j < 16; j++) t[r][ch + j] = tmp.us[j];
  __syncthreads();
  union { uint4 v[2]; u16 us[16]; } o;
#pragma unroll
  for (int j = 0; j < 16; j++) o.us[j] = t[ch + j][r];
  u16* dst = Vt + (size_t)(bh * 64 + r) * 2048 + s0 + ch;
  *(uint4*)dst = o.v[0];
  *(uint4*)(dst + 8) = o.v[1];
}

// ---------------- causal flash attention ----------------
// grid: (32 q-tiles, 64 b*h), 256 threads; wave w handles q rows w*16..w*16+15
__global__ __launch_bounds__(256) void attn_kernel(const u16* __restrict__ Q,
                                                   const u16* __restrict__ K,
                                                   const u16* __restrict__ Vt,
                                                   u16* __restrict__ O) {
  __shared__ u16 Qs[64][72];
  __shared__ u16 Ks[64][72];
  __shared__ u16 Vs[64][72];      // V^T tile: [d][k]
  __shared__ u16 Ps[4][16][72];   // per-wave P staging

  const int qt = blockIdx.x, bh = blockIdx.y;
  const int b = bh >> 4, h = bh & 15;
  const int tid  = threadIdx.x;
  const int lane = tid & 63;
  const int wv   = tid >> 6;
  const int quad = lane >> 4;
  const int cc   = lane & 15;
  const int q0   = qt * 64;

  const int sr = tid >> 2, sch = (tid & 3) * 16;

  { // stage Q tile once
    const u16* src = Q + (size_t)(b * 2048 + q0 + sr) * 1024 + h * 64 + sch;
    uint4 v0 = *(const uint4*)src;
    uint4 v1 = *(const uint4*)(src + 8);
    *(uint4*)&Qs[sr][sch]     = v0;
    *(uint4*)&Qs[sr][sch + 8] = v1;
  }

  float m_i[4], l_i[4];
  f32x4 o_acc[4];
#pragma unroll
  for (int r = 0; r < 4; r++) { m_i[r] = -3.0e38f; l_i[r] = 0.f; }
#pragma unroll
  for (int nt = 0; nt < 4; nt++) o_acc[nt] = (f32x4){0.f, 0.f, 0.f, 0.f};

  const float scale = 0.125f;  // 1/sqrt(64)

  for (int kt = 0; kt <= qt; ++kt) {
    __syncthreads();
    { // stage K tile and V^T tile
      const u16* ksrc = K + (size_t)(b * 2048 + kt * 64 + sr) * 1024 + h * 64 + sch;
      uint4 k0v = *(const uint4*)ksrc;
      uint4 k1v = *(const uint4*)(ksrc + 8);
      const u16* vsrc = Vt + (size_t)(bh * 64 + sr) * 2048 + kt * 64 + sch;
      uint4 v0v = *(const uint4*)vsrc;
      uint4 v1v = *(const uint4*)(vsrc + 8);
      *(uint4*)&Ks[sr][sch]     = k0v;
      *(uint4*)&Ks[sr][sch + 8] = k1v;
      *(uint4*)&Vs[sr][sch]     = v0v;
      *(uint4*)&Vs[sr][sch + 8] = v1v;
    }
    __syncthreads();

    // S = Q K^T  (16 q-rows x 64 keys per wave)
    short8 aq0 = *(const short8*)&Qs[wv * 16 + cc][quad * 8];
    short8 aq1 = *(const short8*)&Qs[wv * 16 + cc][32 + quad * 8];
    f32x4 s[4];
#pragma unroll
    for (int nt = 0; nt < 4; nt++) {
      s[nt] = (f32x4){0.f, 0.f, 0.f, 0.f};
      short8 bk0 = *(const short8*)&Ks[nt * 16 + cc][quad * 8];
      short8 bk1 = *(const short8*)&Ks[nt * 16 + cc][32 + quad * 8];
      s[nt] = __builtin_amdgcn_mfma_f32_16x16x32_bf16(aq0, bk0, s[nt], 0, 0, 0);
      s[nt] = __builtin_amdgcn_mfma_f32_16x16x32_bf16(aq1, bk1, s[nt], 0, 0, 0);
    }

    const bool diag = (kt == qt);
    float sv[4][4];
#pragma unroll
    for (int nt = 0; nt < 4; nt++)
#pragma unroll
      for (int r = 0; r < 4; r++) {
        float v = s[nt][r] * scale;
        if (diag && (nt * 16 + cc > wv * 16 + quad * 4 + r)) v = -3.0e38f;
        sv[nt][r] = v;
      }

    float pv[4][4], alpha[4];
#pragma unroll
    for (int r = 0; r < 4; r++) {
      float mx = fmaxf(fmaxf(sv[0][r], sv[1][r]), fmaxf(sv[2][r], sv[3][r]));
      mx = fmaxf(mx, __shfl_xor(mx, 1));
      mx = fmaxf(mx, __shfl_xor(mx, 2));
      mx = fmaxf(mx, __shfl_xor(mx, 4));
      mx = fmaxf(mx, __shfl_xor(mx, 8));
      float mn = fmaxf(m_i[r], mx);
      float al = __expf(m_i[r] - mn);
      float ls = 0.f;
#pragma unroll
      for (int nt = 0; nt < 4; nt++) {
        float e = __expf(sv[nt][r] - mn);
        pv[nt][r] = e;
        ls += e;
      }
      ls += __shfl_xor(ls, 1);
      ls += __shfl_xor(ls, 2);
      ls += __shfl_xor(ls, 4);
      ls += __shfl_xor(ls, 8);
      l_i[r] = l_i[r] * al + ls;
      m_i[r] = mn;
      alpha[r] = al;
    }

    // rescale O, stage P (C-layout -> A-layout via per-wave LDS)
#pragma unroll
    for (int nt = 0; nt < 4; nt++)
#pragma unroll
      for (int r = 0; r < 4; r++) {
        o_acc[nt][r] *= alpha[r];
        Ps[wv][quad * 4 + r][nt * 16 + cc] = f2b(pv[nt][r]);
      }

    // same-wave LDS: DS pipe is in-order, no barrier needed for own region
    short8 pa0 = *(const short8*)&Ps[wv][cc][quad * 8];
    short8 pa1 = *(const short8*)&Ps[wv][cc][32 + quad * 8];

#pragma unroll
    for (int nt = 0; nt < 4; nt++) {
      short8 bv0 = *(const short8*)&Vs[nt * 16 + cc][quad * 8];
      short8 bv1 = *(const short8*)&Vs[nt * 16 + cc][32 + quad * 8];
      o_acc[nt] = __builtin_amdgcn_mfma_f32_16x16x32_bf16(pa0, bv0, o_acc[nt], 0, 0, 0);
      o_acc[nt] = __builtin_amdgcn_mfma_f32_16x16x32_bf16(pa1, bv1, o_acc[nt], 0, 0, 0);
    }
  }

  // epilogue: O / l, store bf16
#pragma unroll
  for (int nt = 0; nt < 4; nt++)
#pragma unroll
    for (int r = 0; r < 4; r++) {
      float v = o_acc[nt][r] / l_i[r];
      int row = b * 2048 + q0 + wv * 16 + quad * 4 + r;
      O[(size_t)row * 1024 + h * 64 + nt * 16 + cc] = f2b(v);
    }
}

// ---------------- launch ----------------
extern "C" void kernel_launch(void* const* d_in, const int* in_sizes, int n_in,
                              void* d_out, int out_size, void* d_ws, size_t ws_size,
                              hipStream_t stream) {
  const float* x  = (const float*)d_in[0];
  const float* wq = (const float*)d_in[1];
  const float* wk = (const float*)d_in[2];
  const float* wv = (const float*)d_in[3];
  const float* wo = (const float*)d_in[4];
  const int* pos  = (const int*)d_in[5];
  float* out = (float*)d_out;

  char* ws = (char*)d_ws;
  // layout (72 MB total, with aliasing):
  //   [0,16M):   xb (bf16 x)  -> later reused as Vt (x dead after QKV GEMM)
  //   [16M,24M): Wq,Wk,Wv,Wo bf16 (2MB each)
  //   [24M,40M): Q bf16   [40M,56M): K bf16
  //   [56M,72M): V bf16   -> later reused as attn_out (V dead after transpose)
  u16* xb  = (u16*)(ws);
  u16* vt  = (u16*)(ws);
  u16* wqb = (u16*)(ws + (16ull << 20));
  u16* wkb = (u16*)(ws + (18ull << 20));
  u16* wvb = (u16*)(ws + (20ull << 20));
  u16* wob = (u16*)(ws + (22ull << 20));
  u16* Qb  = (u16*)(ws + (24ull << 20));
  u16* Kb  = (u16*)(ws + (40ull << 20));
  u16* Vb  = (u16*)(ws + (56ull << 20));
  u16* aO  = Vb;

  cvt_kernel<<<8192, 256, 0, stream>>>(x, xb, 8388608);
  cvt_kernel<<<1024, 256, 0, stream>>>(wq, wqb, 1048576);
  cvt_kernel<<<1024, 256, 0, stream>>>(wk, wkb, 1048576);
  cvt_kernel<<<1024, 256, 0, stream>>>(wv, wvb, 1048576);
  cvt_kernel<<<1024, 256, 0, stream>>>(wo, wob, 1048576);

  gemm_qkv<<<dim3(24, 64), 256, 0, stream>>>(xb, wqb, wkb, wvb, Qb, Kb, Vb);
  rope_kernel<<<dim3(16384, 2), 256, 0, stream>>>(Qb, Kb, pos);
  transpose_v<<<dim3(32, 64), 256, 0, stream>>>(Vb, vt);
  attn_kernel<<<dim3(32, 64), 256, 0, stream>>>(Qb, Kb, vt, aO);
  gemm_out<<<dim3(8, 64), 256, 0, stream>>>(aO, wob, out);
}

// Round 2
// 383.290 us; speedup vs baseline: 1.1795x; 1.1795x over previous
//
#include <hip/hip_runtime.h>
#include <type_traits>

typedef __attribute__((ext_vector_type(8))) short short8;
typedef __attribute__((ext_vector_type(4))) float f32x4;
typedef unsigned short u16;
typedef unsigned int   u32;

// B=4, S=2048, D=1024, H=16, DK=64, M = B*S = 8192

static __device__ __forceinline__ u16 f2b(float f) {
  u32 u = __builtin_bit_cast(u32, f);
  u = (u + 0x7fffu + ((u >> 16) & 1u)) >> 16;
  return (u16)u;
}
static __device__ __forceinline__ float b2f(u16 h) {
  return __builtin_bit_cast(float, ((u32)h) << 16);
}

typedef __attribute__((address_space(1))) const unsigned int gas_u32;
typedef __attribute__((address_space(3))) unsigned int las_u32;
static __device__ __forceinline__ void glds16(const u16* g, u16* l) {
  // async global->LDS, 16B per lane; LDS dest = wave-uniform base + lane*16
  __builtin_amdgcn_global_load_lds((gas_u32*)g, (las_u32*)l, 16, 0, 0);
}

// ---------------- fused fp32 -> bf16 convert (x + 4 weights) ----------------
__global__ __launch_bounds__(256) void cvt_all(
    const float* __restrict__ x, const float* __restrict__ wq,
    const float* __restrict__ wk, const float* __restrict__ wv,
    const float* __restrict__ wo, u16* __restrict__ xb, u16* __restrict__ wqb,
    u16* __restrict__ wkb, u16* __restrict__ wvb, u16* __restrict__ wob) {
  int u = blockIdx.x * 256 + threadIdx.x;  // unit of 4 floats
  if (u >= 3145728) return;
  const float* src; u16* dst; int off;
  if (u < 2097152) { src = x; dst = xb; off = u; }
  else {
    int t = u - 2097152;
    int w = t >> 18;
    off = t & 0x3FFFF;
    src = (w == 0) ? wq : (w == 1) ? wk : (w == 2) ? wv : wo;
    dst = (w == 0) ? wqb : (w == 1) ? wkb : (w == 2) ? wvb : wob;
  }
  int i = off * 4;
  float4 v = *(const float4*)(src + i);
  union { u16 us[4]; unsigned long long ull; } o;
  o.us[0] = f2b(v.x); o.us[1] = f2b(v.y); o.us[2] = f2b(v.z); o.us[3] = f2b(v.w);
  *(unsigned long long*)(dst + i) = o.ull;
}

// ---------------- GEMM: C[m,n] = sum_k A[m,k]*B[n,k]  (B^T form) ----------
// 128x128 tile, BK=32, 256 threads, global_load_lds(16B) staging into
// XOR-swizzled unpadded LDS (chunk (row,g) stored at row*4 + (g^(row&3))).
template <typename OT>
static __device__ __forceinline__ void gemm_body(const u16* __restrict__ A,
                                                 const u16* __restrict__ B,
                                                 OT* __restrict__ C,
                                                 int m0, int n0) {
  __shared__ u16 As[4096];  // 128 rows x 32 u16 (64B rows)
  __shared__ u16 Bs[4096];

  const int tid  = threadIdx.x;
  const int lane = tid & 63;
  const int wv   = tid >> 6;
  const int quad = lane >> 4;
  const int cc   = lane & 15;
  const int wr   = wv >> 1;
  const int wc   = wv & 1;

  f32x4 acc[4][4];
#pragma unroll
  for (int i = 0; i < 4; i++)
#pragma unroll
    for (int j = 0; j < 4; j++) acc[i][j] = (f32x4){0.f, 0.f, 0.f, 0.f};

  // chunk positions for this lane's two glds instructions per matrix
  const int p0 = wv * 128 + lane;
  const int p1 = p0 + 64;
  const int r0 = p0 >> 2, g0 = (p0 & 3) ^ (r0 & 3);
  const int r1 = p1 >> 2, g1 = (p1 & 3) ^ (r1 & 3);
  const u16* gA0 = A + (size_t)(m0 + r0) * 1024 + g0 * 8;
  const u16* gA1 = A + (size_t)(m0 + r1) * 1024 + g1 * 8;
  const u16* gB0 = B + (size_t)(n0 + r0) * 1024 + g0 * 8;
  const u16* gB1 = B + (size_t)(n0 + r1) * 1024 + g1 * 8;
  u16* lA = As + wv * 1024;  // wave-uniform LDS bases
  u16* lB = Bs + wv * 1024;

  for (int k0 = 0; k0 < 1024; k0 += 32) {
    __syncthreads();
    glds16(gA0 + k0, lA);
    glds16(gA1 + k0, lA + 512);
    glds16(gB0 + k0, lB);
    glds16(gB1 + k0, lB + 512);
    __syncthreads();  // drains vmcnt -> staged data visible to all waves

    short8 af[4], bf[4];
#pragma unroll
    for (int mt = 0; mt < 4; mt++) {
      int ra = wr * 64 + mt * 16 + cc;
      af[mt] = *(const short8*)&As[ra * 32 + ((quad ^ (ra & 3)) * 8)];
    }
#pragma unroll
    for (int nt = 0; nt < 4; nt++) {
      int rb = wc * 64 + nt * 16 + cc;
      bf[nt] = *(const short8*)&Bs[rb * 32 + ((quad ^ (rb & 3)) * 8)];
    }
#pragma unroll
    for (int mt = 0; mt < 4; mt++)
#pragma unroll
      for (int nt = 0; nt < 4; nt++)
        acc[mt][nt] = __builtin_amdgcn_mfma_f32_16x16x32_bf16(af[mt], bf[nt], acc[mt][nt], 0, 0, 0);
  }

#pragma unroll
  for (int mt = 0; mt < 4; mt++)
#pragma unroll
    for (int nt = 0; nt < 4; nt++)
#pragma unroll
      for (int r = 0; r < 4; r++) {
        int row = m0 + wr * 64 + mt * 16 + quad * 4 + r;
        int col = n0 + wc * 64 + nt * 16 + cc;
        if constexpr (std::is_same_v<OT, float>)
          C[(size_t)row * 1024 + col] = acc[mt][nt][r];
        else
          C[(size_t)row * 1024 + col] = f2b(acc[mt][nt][r]);
      }
}

__global__ __launch_bounds__(256) void gemm_qkv(const u16* __restrict__ A,
                                                const u16* __restrict__ Bq,
                                                const u16* __restrict__ Bk,
                                                const u16* __restrict__ Bv,
                                                u16* __restrict__ Q,
                                                u16* __restrict__ K,
                                                u16* __restrict__ V) {
  int sel = blockIdx.x >> 3;
  const u16* B = (sel == 0) ? Bq : (sel == 1) ? Bk : Bv;
  u16* C = (sel == 0) ? Q : (sel == 1) ? K : V;
  gemm_body<u16>(A, B, C, blockIdx.y * 128, (blockIdx.x & 7) * 128);
}

__global__ __launch_bounds__(256) void gemm_out(const u16* __restrict__ A,
                                                const u16* __restrict__ B,
                                                float* __restrict__ C) {
  gemm_body<float>(A, B, C, blockIdx.y * 128, blockIdx.x * 128);
}

// ---------------- RoPE on Q and K (in place, bf16) ----------------
__global__ __launch_bounds__(256) void rope_kernel(u16* __restrict__ Q,
                                                   u16* __restrict__ K,
                                                   const int* __restrict__ pos) {
  u16* T = blockIdx.y ? K : Q;
  int idx = blockIdx.x * 256 + threadIdx.x;
  int row = idx >> 9;
  int p   = idx & 511;
  int i   = p & 31;
  int col = (p >> 5) * 64 + 2 * i;
  int s   = row & 2047;
  float ps  = (float)pos[s];
  float inv = exp2f(-(float)i * 0.41524101186092033f);
  float ang = ps * inv;
  float sn, cs;
  sincosf(ang, &sn, &cs);
  u32 v = *(u32*)(T + (size_t)row * 1024 + col);
  float x1 = b2f((u16)(v & 0xffffu));
  float x2 = b2f((u16)(v >> 16));
  float y1 = x1 * cs - x2 * sn;
  float y2 = x1 * sn + x2 * cs;
  *(u32*)(T + (size_t)row * 1024 + col) = (u32)f2b(y1) | ((u32)f2b(y2) << 16);
}

// ---------------- transpose V: (b,s,h,d) -> Vt[(b,h,d), s] ----------------
__global__ __launch_bounds__(256) void transpose_v(const u16* __restrict__ V,
                                                   u16* __restrict__ Vt) {
  __shared__ u16 t[64][65];
  int s0 = blockIdx.x * 64;
  int bh = blockIdx.y;
  int b = bh >> 4, h = bh & 15;
  int tid = threadIdx.x;
  int r = tid >> 2, ch = (tid & 3) * 16;
  const u16* src = V + (size_t)(b * 2048 + s0 + r) * 1024 + h * 64 + ch;
  union { uint4 v[2]; u16 us[16]; } tmp;
  tmp.v[0] = *(const uint4*)src;
  tmp.v[1] = *(const uint4*)(src + 8);
#pragma unroll
  for (int j = 0; j < 16; j++) t[r][ch + j] = tmp.us[j];
  __syncthreads();
  union { uint4 v[2]; u16 us[16]; } o;
#pragma unroll
  for (int j = 0; j < 16; j++) o.us[j] = t[ch + j][r];
  u16* dst = Vt + (size_t)(bh * 64 + r) * 2048 + s0 + ch;
  *(uint4*)dst = o.v[0];
  *(uint4*)(dst + 8) = o.v[1];
}

// ---------------- causal flash attention V2 ----------------
// 128 q-rows x 128-key tiles; 4 waves x 32 q-rows; Q frags in registers;
// register-prefetch K/V staging; deferred l reduction; LPT (heavy qt first).
// grid: (64 bh, 16 qtile)
__global__ __launch_bounds__(256, 3) void attn_kernel(const u16* __restrict__ Q,
                                                      const u16* __restrict__ K,
                                                      const u16* __restrict__ Vt,
                                                      u16* __restrict__ O) {
  __shared__ u16 Ks[128][72];      // keys x d      (18432 B)
  __shared__ u16 Vs[64][136];      // d x keys      (17408 B)
  __shared__ u16 Ps[4][16][136];   // per-wave P    (17408 B)

  const int bh = blockIdx.x;
  const int qt = 15 - blockIdx.y;  // heavy-first LPT
  const int b = bh >> 4, h = bh & 15;
  const int tid  = threadIdx.x;
  const int lane = tid & 63;
  const int wv   = tid >> 6;
  const int quad = lane >> 4;
  const int cc   = lane & 15;
  const int q0   = qt * 128;

  // Q fragments: A-layout A[m=cc][k=quad*8+j], direct from global
  short8 qf[2][2];
#pragma unroll
  for (int mt = 0; mt < 2; mt++) {
    const u16* qp = Q + (size_t)(b * 2048 + q0 + wv * 32 + mt * 16 + cc) * 1024 + h * 64;
    qf[mt][0] = *(const short8*)(qp + quad * 8);
    qf[mt][1] = *(const short8*)(qp + 32 + quad * 8);
  }

  f32x4 o_acc[2][4];
  float m_i[2][4], l_i[2][4];
#pragma unroll
  for (int mt = 0; mt < 2; mt++) {
#pragma unroll
    for (int r = 0; r < 4; r++) { m_i[mt][r] = -3.0e38f; l_i[mt][r] = 0.f; }
#pragma unroll
    for (int nt = 0; nt < 4; nt++) o_acc[mt][nt] = (f32x4){0.f, 0.f, 0.f, 0.f};
  }

  // staging addresses
  const int krow = tid >> 1, kc = (tid & 1) * 32;
  const u16* Kg = K + ((size_t)(b * 2048) + krow) * 1024 + h * 64 + kc;
  const int vrow = tid >> 2, vc = (tid & 3) * 32;
  const u16* Vg = Vt + ((size_t)(bh * 64) + vrow) * 2048 + vc;

  const int nkt = qt + 1;
  uint4 kpf[4], vpf[4];
#pragma unroll
  for (int j = 0; j < 4; j++) {
    kpf[j] = *(const uint4*)(Kg + j * 8);
    vpf[j] = *(const uint4*)(Vg + j * 8);
  }

  for (int kt = 0; kt < nkt; ++kt) {
    __syncthreads();  // prior iter's LDS reads complete
#pragma unroll
    for (int j = 0; j < 4; j++) {
      *(uint4*)&Ks[krow][kc + j * 8] = kpf[j];
      *(uint4*)&Vs[vrow][vc + j * 8] = vpf[j];
    }
    __syncthreads();

    if (kt + 1 < nkt) {  // prefetch next tile; overlaps with compute below
      const u16* Kg2 = Kg + (size_t)(kt + 1) * 131072;
      const u16* Vg2 = Vg + (kt + 1) * 128;
#pragma unroll
      for (int j = 0; j < 4; j++) {
        kpf[j] = *(const uint4*)(Kg2 + j * 8);
        vpf[j] = *(const uint4*)(Vg2 + j * 8);
      }
    }

    const bool diag = (kt == qt);

#pragma unroll
    for (int mt = 0; mt < 2; ++mt) {
      // S = Q K^T : 16 q-rows x 128 keys
      f32x4 s[8];
#pragma unroll
      for (int nt = 0; nt < 8; ++nt) {
        short8 bk0 = *(const short8*)&Ks[nt * 16 + cc][quad * 8];
        short8 bk1 = *(const short8*)&Ks[nt * 16 + cc][32 + quad * 8];
        f32x4 z = (f32x4){0.f, 0.f, 0.f, 0.f};
        z = __builtin_amdgcn_mfma_f32_16x16x32_bf16(qf[mt][0], bk0, z, 0, 0, 0);
        s[nt] = __builtin_amdgcn_mfma_f32_16x16x32_bf16(qf[mt][1], bk1, z, 0, 0, 0);
      }

      const int rb = wv * 32 + mt * 16 + quad * 4;  // local row base
#pragma unroll
      for (int nt = 0; nt < 8; ++nt)
#pragma unroll
        for (int r = 0; r < 4; ++r) {
          float v = s[nt][r] * 0.125f;
          if (diag && (nt * 16 + cc > rb + r)) v = -3.0e38f;
          s[nt][r] = v;
        }

#pragma unroll
      for (int r = 0; r < 4; ++r) {
        float mx = s[0][r];
#pragma unroll
        for (int nt = 1; nt < 8; ++nt) mx = fmaxf(mx, s[nt][r]);
        mx = fmaxf(mx, __shfl_xor(mx, 1));
        mx = fmaxf(mx, __shfl_xor(mx, 2));
        mx = fmaxf(mx, __shfl_xor(mx, 4));
        mx = fmaxf(mx, __shfl_xor(mx, 8));
        float mn = fmaxf(m_i[mt][r], mx);
        float al = __expf(m_i[mt][r] - mn);
        m_i[mt][r] = mn;
        float ps = 0.f;
#pragma unroll
        for (int nt = 0; nt < 8; ++nt) {
          float e = __expf(s[nt][r] - mn);
          ps += e;
          Ps[wv][quad * 4 + r][nt * 16 + cc] = f2b(e);
        }
        l_i[mt][r] = l_i[mt][r] * al + ps;  // per-lane partial; reduced at end
#pragma unroll
        for (int nt = 0; nt < 4; ++nt) o_acc[mt][nt][r] *= al;
      }

      // P: C-layout -> A-layout via per-wave LDS (same-wave, no barrier)
      short8 pa[4];
#pragma unroll
      for (int ks = 0; ks < 4; ++ks)
        pa[ks] = *(const short8*)&Ps[wv][cc][ks * 32 + quad * 8];

#pragma unroll
      for (int nt = 0; nt < 4; ++nt)
#pragma unroll
        for (int ks = 0; ks < 4; ++ks) {
          short8 bv = *(const short8*)&Vs[nt * 16 + cc][ks * 32 + quad * 8];
          o_acc[mt][nt] = __builtin_amdgcn_mfma_f32_16x16x32_bf16(pa[ks], bv, o_acc[mt][nt], 0, 0, 0);
        }
    }
  }

  // final cross-lane l reduction + normalize + store
#pragma unroll
  for (int mt = 0; mt < 2; ++mt)
#pragma unroll
    for (int r = 0; r < 4; ++r) {
      float l = l_i[mt][r];
      l += __shfl_xor(l, 1);
      l += __shfl_xor(l, 2);
      l += __shfl_xor(l, 4);
      l += __shfl_xor(l, 8);
      float inv = 1.0f / l;
      int row = b * 2048 + q0 + wv * 32 + mt * 16 + quad * 4 + r;
#pragma unroll
      for (int nt = 0; nt < 4; ++nt)
        O[(size_t)row * 1024 + h * 64 + nt * 16 + cc] = f2b(o_acc[mt][nt][r] * inv);
    }
}

// ---------------- launch ----------------
extern "C" void kernel_launch(void* const* d_in, const int* in_sizes, int n_in,
                              void* d_out, int out_size, void* d_ws, size_t ws_size,
                              hipStream_t stream) {
  const float* x  = (const float*)d_in[0];
  const float* wq = (const float*)d_in[1];
  const float* wk = (const float*)d_in[2];
  const float* wv = (const float*)d_in[3];
  const float* wo = (const float*)d_in[4];
  const int* pos  = (const int*)d_in[5];
  float* out = (float*)d_out;

  char* ws = (char*)d_ws;
  // [0,16M): xb -> later Vt   [16M,24M): weights bf16
  // [24M,40M): Q  [40M,56M): K  [56M,72M): V -> later attn_out
  u16* xb  = (u16*)(ws);
  u16* vt  = (u16*)(ws);
  u16* wqb = (u16*)(ws + (16ull << 20));
  u16* wkb = (u16*)(ws + (18ull << 20));
  u16* wvb = (u16*)(ws + (20ull << 20));
  u16* wob = (u16*)(ws + (22ull << 20));
  u16* Qb  = (u16*)(ws + (24ull << 20));
  u16* Kb  = (u16*)(ws + (40ull << 20));
  u16* Vb  = (u16*)(ws + (56ull << 20));
  u16* aO  = Vb;

  cvt_all<<<12288, 256, 0, stream>>>(x, wq, wk, wv, wo, xb, wqb, wkb, wvb, wob);
  gemm_qkv<<<dim3(24, 64), 256, 0, stream>>>(xb, wqb, wkb, wvb, Qb, Kb, Vb);
  rope_kernel<<<dim3(16384, 2), 256, 0, stream>>>(Qb, Kb, pos);
  transpose_v<<<dim3(32, 64), 256, 0, stream>>>(Vb, vt);
  attn_kernel<<<dim3(64, 16), 256, 0, stream>>>(Qb, Kb, vt, aO);
  gemm_out<<<dim3(8, 64), 256, 0, stream>>>(aO, wob, out);
}

// Round 3
// 344.518 us; speedup vs baseline: 1.3123x; 1.1125x over previous
//
#include <hip/hip_runtime.h>
#include <type_traits>

typedef __attribute__((ext_vector_type(8))) short short8;
typedef __attribute__((ext_vector_type(4))) float f32x4;
typedef unsigned short u16;
typedef unsigned int   u32;
typedef unsigned long long u64;

// B=4, S=2048, D=1024, H=16, DK=64, M = B*S = 8192

static __device__ __forceinline__ u16 f2b(float f) {
  u32 u = __builtin_bit_cast(u32, f);
  u = (u + 0x7fffu + ((u >> 16) & 1u)) >> 16;
  return (u16)u;
}
static __device__ __forceinline__ float b2f(u16 h) {
  return __builtin_bit_cast(float, ((u32)h) << 16);
}

typedef __attribute__((address_space(1))) const unsigned int gas_u32;
typedef __attribute__((address_space(3))) unsigned int las_u32;
static __device__ __forceinline__ void glds16(const u16* g, u16* l) {
  __builtin_amdgcn_global_load_lds((gas_u32*)g, (las_u32*)l, 16, 0, 0);
}

// ---------------- fused fp32 -> bf16 convert (x + 4 weights) ----------------
__global__ __launch_bounds__(256) void cvt_all(
    const float* __restrict__ x, const float* __restrict__ wq,
    const float* __restrict__ wk, const float* __restrict__ wv,
    const float* __restrict__ wo, u16* __restrict__ xb, u16* __restrict__ wqb,
    u16* __restrict__ wkb, u16* __restrict__ wvb, u16* __restrict__ wob) {
  int u = blockIdx.x * 256 + threadIdx.x;  // unit of 4 floats
  if (u >= 3145728) return;
  const float* src; u16* dst; int off;
  if (u < 2097152) { src = x; dst = xb; off = u; }
  else {
    int t = u - 2097152;
    int w = t >> 18;
    off = t & 0x3FFFF;
    src = (w == 0) ? wq : (w == 1) ? wk : (w == 2) ? wv : wo;
    dst = (w == 0) ? wqb : (w == 1) ? wkb : (w == 2) ? wvb : wob;
  }
  int i = off * 4;
  float4 v = *(const float4*)(src + i);
  union { u16 us[4]; u64 ull; } o;
  o.us[0] = f2b(v.x); o.us[1] = f2b(v.y); o.us[2] = f2b(v.z); o.us[3] = f2b(v.w);
  *(u64*)(dst + i) = o.ull;
}

// ---------------- GEMM: C[m,n] = sum_k A[m,k]*B[n,k]  (B^T form) ----------
// 128x128 tile, BK=32, 256 threads, global_load_lds(16B) staging into
// XOR-swizzled unpadded LDS (chunk (row,g) stored at row*4 + (g^(row&3))).
template <typename OT>
static __device__ __forceinline__ void gemm_body(const u16* __restrict__ A,
                                                 const u16* __restrict__ B,
                                                 OT* __restrict__ C,
                                                 int m0, int n0) {
  __shared__ u16 As[4096];
  __shared__ u16 Bs[4096];

  const int tid  = threadIdx.x;
  const int lane = tid & 63;
  const int wv   = tid >> 6;
  const int quad = lane >> 4;
  const int cc   = lane & 15;
  const int wr   = wv >> 1;
  const int wc   = wv & 1;

  f32x4 acc[4][4];
#pragma unroll
  for (int i = 0; i < 4; i++)
#pragma unroll
    for (int j = 0; j < 4; j++) acc[i][j] = (f32x4){0.f, 0.f, 0.f, 0.f};

  const int p0 = wv * 128 + lane;
  const int p1 = p0 + 64;
  const int r0 = p0 >> 2, g0 = (p0 & 3) ^ (r0 & 3);
  const int r1 = p1 >> 2, g1 = (p1 & 3) ^ (r1 & 3);
  const u16* gA0 = A + (size_t)(m0 + r0) * 1024 + g0 * 8;
  const u16* gA1 = A + (size_t)(m0 + r1) * 1024 + g1 * 8;
  const u16* gB0 = B + (size_t)(n0 + r0) * 1024 + g0 * 8;
  const u16* gB1 = B + (size_t)(n0 + r1) * 1024 + g1 * 8;
  u16* lA = As + wv * 1024;
  u16* lB = Bs + wv * 1024;

  for (int k0 = 0; k0 < 1024; k0 += 32) {
    __syncthreads();
    glds16(gA0 + k0, lA);
    glds16(gA1 + k0, lA + 512);
    glds16(gB0 + k0, lB);
    glds16(gB1 + k0, lB + 512);
    __syncthreads();

    short8 af[4], bf[4];
#pragma unroll
    for (int mt = 0; mt < 4; mt++) {
      int ra = wr * 64 + mt * 16 + cc;
      af[mt] = *(const short8*)&As[ra * 32 + ((quad ^ (ra & 3)) * 8)];
    }
#pragma unroll
    for (int nt = 0; nt < 4; nt++) {
      int rb = wc * 64 + nt * 16 + cc;
      bf[nt] = *(const short8*)&Bs[rb * 32 + ((quad ^ (rb & 3)) * 8)];
    }
#pragma unroll
    for (int mt = 0; mt < 4; mt++)
#pragma unroll
      for (int nt = 0; nt < 4; nt++)
        acc[mt][nt] = __builtin_amdgcn_mfma_f32_16x16x32_bf16(af[mt], bf[nt], acc[mt][nt], 0, 0, 0);
  }

#pragma unroll
  for (int mt = 0; mt < 4; mt++)
#pragma unroll
    for (int nt = 0; nt < 4; nt++)
#pragma unroll
      for (int r = 0; r < 4; r++) {
        int row = m0 + wr * 64 + mt * 16 + quad * 4 + r;
        int col = n0 + wc * 64 + nt * 16 + cc;
        if constexpr (std::is_same_v<OT, float>)
          C[(size_t)row * 1024 + col] = acc[mt][nt][r];
        else
          C[(size_t)row * 1024 + col] = f2b(acc[mt][nt][r]);
      }
}

__global__ __launch_bounds__(256) void gemm_qkv(const u16* __restrict__ A,
                                                const u16* __restrict__ Bq,
                                                const u16* __restrict__ Bk,
                                                const u16* __restrict__ Bv,
                                                u16* __restrict__ Q,
                                                u16* __restrict__ K,
                                                u16* __restrict__ V) {
  int sel = blockIdx.x >> 3;
  const u16* B = (sel == 0) ? Bq : (sel == 1) ? Bk : Bv;
  u16* C = (sel == 0) ? Q : (sel == 1) ? K : V;
  gemm_body<u16>(A, B, C, blockIdx.y * 128, (blockIdx.x & 7) * 128);
}

__global__ __launch_bounds__(256) void gemm_out(const u16* __restrict__ A,
                                                const u16* __restrict__ B,
                                                float* __restrict__ C) {
  gemm_body<float>(A, B, C, blockIdx.y * 128, blockIdx.x * 128);
}

// ---------------- RoPE on Q and K (in place, bf16) ----------------
// Q additionally pre-scaled by 1/sqrt(dk)=0.125 (exact in bf16) so the
// attention kernel can skip the score scaling.
__global__ __launch_bounds__(256) void rope_kernel(u16* __restrict__ Q,
                                                   u16* __restrict__ K,
                                                   const int* __restrict__ pos) {
  u16* T = blockIdx.y ? K : Q;
  const float sc = blockIdx.y ? 1.0f : 0.125f;
  int idx = blockIdx.x * 256 + threadIdx.x;
  int row = idx >> 9;
  int p   = idx & 511;
  int i   = p & 31;
  int col = (p >> 5) * 64 + 2 * i;
  int s   = row & 2047;
  float ps  = (float)pos[s];
  float inv = exp2f(-(float)i * 0.41524101186092033f);
  float ang = ps * inv;
  float sn, cs;
  sincosf(ang, &sn, &cs);
  u32 v = *(u32*)(T + (size_t)row * 1024 + col);
  float x1 = b2f((u16)(v & 0xffffu));
  float x2 = b2f((u16)(v >> 16));
  float y1 = (x1 * cs - x2 * sn) * sc;
  float y2 = (x1 * sn + x2 * cs) * sc;
  *(u32*)(T + (size_t)row * 1024 + col) = (u32)f2b(y1) | ((u32)f2b(y2) << 16);
}

// ---------------- transpose V: (b,s,h,d) -> Vt[(b,h,d), s] ----------------
__global__ __launch_bounds__(256) void transpose_v(const u16* __restrict__ V,
                                                   u16* __restrict__ Vt) {
  __shared__ u16 t[64][65];
  int s0 = blockIdx.x * 64;
  int bh = blockIdx.y;
  int b = bh >> 4, h = bh & 15;
  int tid = threadIdx.x;
  int r = tid >> 2, ch = (tid & 3) * 16;
  const u16* src = V + (size_t)(b * 2048 + s0 + r) * 1024 + h * 64 + ch;
  union { uint4 v[2]; u16 us[16]; } tmp;
  tmp.v[0] = *(const uint4*)src;
  tmp.v[1] = *(const uint4*)(src + 8);
#pragma unroll
  for (int j = 0; j < 16; j++) t[r][ch + j] = tmp.us[j];
  __syncthreads();
  union { uint4 v[2]; u16 us[16]; } o;
#pragma unroll
  for (int j = 0; j < 16; j++) o.us[j] = t[ch + j][r];
  u16* dst = Vt + (size_t)(bh * 64 + r) * 2048 + s0 + ch;
  *(uint4*)dst = o.v[0];
  *(uint4*)(dst + 8) = o.v[1];
}

// ---------------- causal flash attention V3 (S^T formulation) ----------------
// S^T = K·Q^T via mfma(kf, qf): C rows = keys (quad*4+r), cols = q (cc).
// Row-max/sum: 31 in-lane ops + 2 shfls (vs 32 shfl rounds in V2).
// Stats per lane keyed by q=cc; alpha/1-l moved to o_acc row layout via shfl.
// No forced occupancy bound -> compiler allocates freely, no spill.
// grid: (64 bh, 16 qtile); LPT: heavy q-tiles first.
__global__ __launch_bounds__(256) void attn_kernel(const u16* __restrict__ Q,
                                                   const u16* __restrict__ K,
                                                   const u16* __restrict__ Vt,
                                                   u16* __restrict__ O) {
  __shared__ u16 Ks[128][72];      // keys x d      (18432 B)
  __shared__ u16 Vs[64][136];      // d x keys      (17408 B)
  __shared__ u16 Ps[4][16][136];   // per-wave P [q][k] (17408 B)

  const int bh = blockIdx.x;
  const int qt = 15 - blockIdx.y;  // heavy-first LPT
  const int b = bh >> 4, h = bh & 15;
  const int tid  = threadIdx.x;
  const int lane = tid & 63;
  const int wv   = tid >> 6;
  const int quad = lane >> 4;
  const int cc   = lane & 15;
  const int q0   = qt * 128;

  // Q fragments (B-operand layout B[n=cc][k=quad*8+j]); Q pre-scaled by 0.125
  short8 qf[2][2];
#pragma unroll
  for (int mt = 0; mt < 2; mt++) {
    const u16* qp = Q + (size_t)(b * 2048 + q0 + wv * 32 + mt * 16 + cc) * 1024 + h * 64;
    qf[mt][0] = *(const short8*)(qp + quad * 8);
    qf[mt][1] = *(const short8*)(qp + 32 + quad * 8);
  }

  f32x4 o_acc[2][4];
  float m_i[2] = {-3.0e38f, -3.0e38f}, l_i[2] = {0.f, 0.f};
#pragma unroll
  for (int mt = 0; mt < 2; mt++)
#pragma unroll
    for (int nt = 0; nt < 4; nt++) o_acc[mt][nt] = (f32x4){0.f, 0.f, 0.f, 0.f};

  // staging addresses
  const int krow = tid >> 1, kc = (tid & 1) * 32;
  const u16* Kg = K + ((size_t)(b * 2048) + krow) * 1024 + h * 64 + kc;
  const int vrow = tid >> 2, vc = (tid & 3) * 32;
  const u16* Vg = Vt + ((size_t)(bh * 64) + vrow) * 2048 + vc;

  const int nkt = qt + 1;
  uint4 kpf[4], vpf[4];
#pragma unroll
  for (int j = 0; j < 4; j++) {
    kpf[j] = *(const uint4*)(Kg + j * 8);
    vpf[j] = *(const uint4*)(Vg + j * 8);
  }

  for (int kt = 0; kt < nkt; ++kt) {
    __syncthreads();
#pragma unroll
    for (int j = 0; j < 4; j++) {
      *(uint4*)&Ks[krow][kc + j * 8] = kpf[j];
      *(uint4*)&Vs[vrow][vc + j * 8] = vpf[j];
    }
    __syncthreads();

    if (kt + 1 < nkt) {  // prefetch next tile into registers; overlaps compute
      Kg += 131072;
      Vg += 128;
#pragma unroll
      for (int j = 0; j < 4; j++) {
        kpf[j] = *(const uint4*)(Kg + j * 8);
        vpf[j] = *(const uint4*)(Vg + j * 8);
      }
    }

    const bool diag = (kt == qt);

#pragma unroll
    for (int mt = 0; mt < 2; ++mt) {
      // S^T = K Q^T : rows=keys, cols=q
      f32x4 s[8];
#pragma unroll
      for (int nt = 0; nt < 8; ++nt) {
        short8 bk0 = *(const short8*)&Ks[nt * 16 + cc][quad * 8];
        short8 bk1 = *(const short8*)&Ks[nt * 16 + cc][32 + quad * 8];
        f32x4 z = (f32x4){0.f, 0.f, 0.f, 0.f};
        z = __builtin_amdgcn_mfma_f32_16x16x32_bf16(bk0, qf[mt][0], z, 0, 0, 0);
        s[nt] = __builtin_amdgcn_mfma_f32_16x16x32_bf16(bk1, qf[mt][1], z, 0, 0, 0);
      }

      const int qg = q0 + wv * 32 + mt * 16 + cc;  // this lane's q (global)
      const int kb = kt * 128 + quad * 4;          // this lane's key base
      float mx = -3.0e38f;
#pragma unroll
      for (int nt = 0; nt < 8; ++nt)
#pragma unroll
        for (int r = 0; r < 4; ++r) {
          if (diag && (kb + nt * 16 + r > qg)) s[nt][r] = -3.0e38f;
          mx = fmaxf(mx, s[nt][r]);
        }
      // reduce across quads (keys) -> true row max for q=cc
      mx = fmaxf(mx, __shfl_xor(mx, 16));
      mx = fmaxf(mx, __shfl_xor(mx, 32));
      const float mn = fmaxf(m_i[mt], mx);
      const float al = __expf(m_i[mt] - mn);  // identical across quads
      m_i[mt] = mn;

      float ps = 0.f;
#pragma unroll
      for (int nt = 0; nt < 8; ++nt) {
        float e0 = __expf(s[nt][0] - mn);
        float e1 = __expf(s[nt][1] - mn);
        float e2 = __expf(s[nt][2] - mn);
        float e3 = __expf(s[nt][3] - mn);
        ps += (e0 + e1) + (e2 + e3);
        u64 pk = (u64)f2b(e0) | ((u64)f2b(e1) << 16) |
                 ((u64)f2b(e2) << 32) | ((u64)f2b(e3) << 48);
        *(u64*)&Ps[wv][cc][nt * 16 + quad * 4] = pk;  // P[q=cc][k], 8B packed
      }
      l_i[mt] = l_i[mt] * al + ps;  // per-lane partial (quads summed at end)

      // alpha indexed by o_acc row (quad*4+r): lane permutation via shfl
      f32x4 al4;
#pragma unroll
      for (int r = 0; r < 4; ++r) al4[r] = __shfl(al, quad * 4 + r);
#pragma unroll
      for (int nt = 0; nt < 4; ++nt) o_acc[mt][nt] *= al4;

      // P: [q][k] LDS -> A-fragment (same-wave region, DS pipe in-order)
      short8 pa[4];
#pragma unroll
      for (int ks = 0; ks < 4; ++ks)
        pa[ks] = *(const short8*)&Ps[wv][cc][ks * 32 + quad * 8];

#pragma unroll
      for (int nt = 0; nt < 4; ++nt)
#pragma unroll
        for (int ks = 0; ks < 4; ++ks) {
          short8 bv = *(const short8*)&Vs[nt * 16 + cc][ks * 32 + quad * 8];
          o_acc[mt][nt] = __builtin_amdgcn_mfma_f32_16x16x32_bf16(pa[ks], bv, o_acc[mt][nt], 0, 0, 0);
        }
    }
  }

  // epilogue: reduce l across quads, permute to row layout, normalize, store
#pragma unroll
  for (int mt = 0; mt < 2; ++mt) {
    float l = l_i[mt];
    l += __shfl_xor(l, 16);
    l += __shfl_xor(l, 32);
    const float linv = 1.0f / l;
    f32x4 li4;
#pragma unroll
    for (int r = 0; r < 4; ++r) li4[r] = __shfl(linv, quad * 4 + r);
    const int rowb = b * 2048 + q0 + wv * 32 + mt * 16 + quad * 4;
#pragma unroll
    for (int nt = 0; nt < 4; ++nt)
#pragma unroll
      for (int r = 0; r < 4; ++r)
        O[(size_t)(rowb + r) * 1024 + h * 64 + nt * 16 + cc] = f2b(o_acc[mt][nt][r] * li4[r]);
  }
}

// ---------------- launch ----------------
extern "C" void kernel_launch(void* const* d_in, const int* in_sizes, int n_in,
                              void* d_out, int out_size, void* d_ws, size_t ws_size,
                              hipStream_t stream) {
  const float* x  = (const float*)d_in[0];
  const float* wq = (const float*)d_in[1];
  const float* wk = (const float*)d_in[2];
  const float* wv = (const float*)d_in[3];
  const float* wo = (const float*)d_in[4];
  const int* pos  = (const int*)d_in[5];
  float* out = (float*)d_out;

  char* ws = (char*)d_ws;
  // [0,16M): xb -> later Vt   [16M,24M): weights bf16
  // [24M,40M): Q  [40M,56M): K  [56M,72M): V -> later attn_out
  u16* xb  = (u16*)(ws);
  u16* vt  = (u16*)(ws);
  u16* wqb = (u16*)(ws + (16ull << 20));
  u16* wkb = (u16*)(ws + (18ull << 20));
  u16* wvb = (u16*)(ws + (20ull << 20));
  u16* wob = (u16*)(ws + (22ull << 20));
  u16* Qb  = (u16*)(ws + (24ull << 20));
  u16* Kb  = (u16*)(ws + (40ull << 20));
  u16* Vb  = (u16*)(ws + (56ull << 20));
  u16* aO  = Vb;

  cvt_all<<<12288, 256, 0, stream>>>(x, wq, wk, wv, wo, xb, wqb, wkb, wvb, wob);
  gemm_qkv<<<dim3(24, 64), 256, 0, stream>>>(xb, wqb, wkb, wvb, Qb, Kb, Vb);
  rope_kernel<<<dim3(16384, 2), 256, 0, stream>>>(Qb, Kb, pos);
  transpose_v<<<dim3(32, 64), 256, 0, stream>>>(Vb, vt);
  attn_kernel<<<dim3(64, 16), 256, 0, stream>>>(Qb, Kb, vt, aO);
  gemm_out<<<dim3(8, 64), 256, 0, stream>>>(aO, wob, out);
}

// Round 5
// 299.011 us; speedup vs baseline: 1.5120x; 1.1522x over previous
//
#include <hip/hip_runtime.h>
#include <hip/hip_bf16.h>
#include <type_traits>

typedef __attribute__((ext_vector_type(8))) short short8;
typedef __attribute__((ext_vector_type(4))) short s16x4;
typedef __attribute__((ext_vector_type(4))) float f32x4;
typedef unsigned short u16;
typedef unsigned int   u32;
typedef unsigned long long u64;

// B=4, S=2048, D=1024, H=16, DK=64, M = B*S = 8192

#if __has_builtin(__builtin_amdgcn_mfma_f32_16x16x16bf16_1k)
#define MFMA16(a, b, c) __builtin_amdgcn_mfma_f32_16x16x16bf16_1k(a, b, c, 0, 0, 0)
#define HAVE_MFMA16 1
#elif __has_builtin(__builtin_amdgcn_mfma_f32_16x16x16_bf16)
#define MFMA16(a, b, c) __builtin_amdgcn_mfma_f32_16x16x16_bf16(a, b, c, 0, 0, 0)
#define HAVE_MFMA16 1
#else
#define HAVE_MFMA16 0
#endif

static __device__ __forceinline__ u16 f2b(float f) {
  u32 u = __builtin_bit_cast(u32, f);
  u = (u + 0x7fffu + ((u >> 16) & 1u)) >> 16;
  return (u16)u;
}
static __device__ __forceinline__ float b2f(u16 h) {
  return __builtin_bit_cast(float, ((u32)h) << 16);
}
static __device__ __forceinline__ u32 pkbf(float a, float b) {
  // v_cvt_pk_bf16_f32; union pun (bit_cast rejects non-trivially-copyable)
  union { __hip_bfloat162 t; u32 u; } c;
  c.t = __float22bfloat162_rn(make_float2(a, b));
  return c.u;
}

typedef __attribute__((address_space(1))) const unsigned int gas_u32;
typedef __attribute__((address_space(3))) unsigned int las_u32;
static __device__ __forceinline__ void glds16(const u16* g, u16* l) {
  __builtin_amdgcn_global_load_lds((gas_u32*)g, (las_u32*)l, 16, 0, 0);
}

// ---------------- fused fp32 -> bf16 convert (x + 4 weights) ----------------
__global__ __launch_bounds__(256) void cvt_all(
    const float* __restrict__ x, const float* __restrict__ wq,
    const float* __restrict__ wk, const float* __restrict__ wv,
    const float* __restrict__ wo, u16* __restrict__ xb, u16* __restrict__ wqb,
    u16* __restrict__ wkb, u16* __restrict__ wvb, u16* __restrict__ wob) {
  int u = blockIdx.x * 256 + threadIdx.x;  // unit of 4 floats
  if (u >= 3145728) return;
  const float* src; u16* dst; int off;
  if (u < 2097152) { src = x; dst = xb; off = u; }
  else {
    int t = u - 2097152;
    int w = t >> 18;
    off = t & 0x3FFFF;
    src = (w == 0) ? wq : (w == 1) ? wk : (w == 2) ? wv : wo;
    dst = (w == 0) ? wqb : (w == 1) ? wkb : (w == 2) ? wvb : wob;
  }
  int i = off * 4;
  float4 v = *(const float4*)(src + i);
  union { u16 us[4]; u64 ull; } o;
  o.us[0] = f2b(v.x); o.us[1] = f2b(v.y); o.us[2] = f2b(v.z); o.us[3] = f2b(v.w);
  *(u64*)(dst + i) = o.ull;
}

// ---------------- GEMM: C[m,n] = sum_k A[m,k]*B[n,k]  (B^T form) ----------
template <typename OT>
static __device__ __forceinline__ void gemm_body(const u16* __restrict__ A,
                                                 const u16* __restrict__ B,
                                                 OT* __restrict__ C,
                                                 int m0, int n0) {
  __shared__ u16 As[4096];
  __shared__ u16 Bs[4096];

  const int tid  = threadIdx.x;
  const int lane = tid & 63;
  const int wv   = tid >> 6;
  const int quad = lane >> 4;
  const int cc   = lane & 15;
  const int wr   = wv >> 1;
  const int wc   = wv & 1;

  f32x4 acc[4][4];
#pragma unroll
  for (int i = 0; i < 4; i++)
#pragma unroll
    for (int j = 0; j < 4; j++) acc[i][j] = (f32x4){0.f, 0.f, 0.f, 0.f};

  const int p0 = wv * 128 + lane;
  const int p1 = p0 + 64;
  const int r0 = p0 >> 2, g0 = (p0 & 3) ^ (r0 & 3);
  const int r1 = p1 >> 2, g1 = (p1 & 3) ^ (r1 & 3);
  const u16* gA0 = A + (size_t)(m0 + r0) * 1024 + g0 * 8;
  const u16* gA1 = A + (size_t)(m0 + r1) * 1024 + g1 * 8;
  const u16* gB0 = B + (size_t)(n0 + r0) * 1024 + g0 * 8;
  const u16* gB1 = B + (size_t)(n0 + r1) * 1024 + g1 * 8;
  u16* lA = As + wv * 1024;
  u16* lB = Bs + wv * 1024;

  for (int k0 = 0; k0 < 1024; k0 += 32) {
    __syncthreads();
    glds16(gA0 + k0, lA);
    glds16(gA1 + k0, lA + 512);
    glds16(gB0 + k0, lB);
    glds16(gB1 + k0, lB + 512);
    __syncthreads();

    short8 af[4], bf[4];
#pragma unroll
    for (int mt = 0; mt < 4; mt++) {
      int ra = wr * 64 + mt * 16 + cc;
      af[mt] = *(const short8*)&As[ra * 32 + ((quad ^ (ra & 3)) * 8)];
    }
#pragma unroll
    for (int nt = 0; nt < 4; nt++) {
      int rb = wc * 64 + nt * 16 + cc;
      bf[nt] = *(const short8*)&Bs[rb * 32 + ((quad ^ (rb & 3)) * 8)];
    }
#pragma unroll
    for (int mt = 0; mt < 4; mt++)
#pragma unroll
      for (int nt = 0; nt < 4; nt++)
        acc[mt][nt] = __builtin_amdgcn_mfma_f32_16x16x32_bf16(af[mt], bf[nt], acc[mt][nt], 0, 0, 0);
  }

#pragma unroll
  for (int mt = 0; mt < 4; mt++)
#pragma unroll
    for (int nt = 0; nt < 4; nt++)
#pragma unroll
      for (int r = 0; r < 4; r++) {
        int row = m0 + wr * 64 + mt * 16 + quad * 4 + r;
        int col = n0 + wc * 64 + nt * 16 + cc;
        if constexpr (std::is_same_v<OT, float>)
          C[(size_t)row * 1024 + col] = acc[mt][nt][r];
        else
          C[(size_t)row * 1024 + col] = f2b(acc[mt][nt][r]);
      }
}

__global__ __launch_bounds__(256) void gemm_qkv(const u16* __restrict__ A,
                                                const u16* __restrict__ Bq,
                                                const u16* __restrict__ Bk,
                                                const u16* __restrict__ Bv,
                                                u16* __restrict__ Q,
                                                u16* __restrict__ K,
                                                u16* __restrict__ V) {
  int sel = blockIdx.x >> 3;
  const u16* B = (sel == 0) ? Bq : (sel == 1) ? Bk : Bv;
  u16* C = (sel == 0) ? Q : (sel == 1) ? K : V;
  gemm_body<u16>(A, B, C, blockIdx.y * 128, (blockIdx.x & 7) * 128);
}

__global__ __launch_bounds__(256) void gemm_out(const u16* __restrict__ A,
                                                const u16* __restrict__ B,
                                                float* __restrict__ C) {
  gemm_body<float>(A, B, C, blockIdx.y * 128, blockIdx.x * 128);
}

// ---------------- RoPE on Q and K (in place, bf16); Q pre-scaled 0.125 -----
__global__ __launch_bounds__(256) void rope_kernel(u16* __restrict__ Q,
                                                   u16* __restrict__ K,
                                                   const int* __restrict__ pos) {
  u16* T = blockIdx.y ? K : Q;
  const float sc = blockIdx.y ? 1.0f : 0.125f;
  int idx = blockIdx.x * 256 + threadIdx.x;
  int row = idx >> 9;
  int p   = idx & 511;
  int i   = p & 31;
  int col = (p >> 5) * 64 + 2 * i;
  int s   = row & 2047;
  float ps  = (float)pos[s];
  float inv = exp2f(-(float)i * 0.41524101186092033f);
  float ang = ps * inv;
  float sn, cs;
  sincosf(ang, &sn, &cs);
  u32 v = *(u32*)(T + (size_t)row * 1024 + col);
  float x1 = b2f((u16)(v & 0xffffu));
  float x2 = b2f((u16)(v >> 16));
  float y1 = (x1 * cs - x2 * sn) * sc;
  float y2 = (x1 * sn + x2 * cs) * sc;
  *(u32*)(T + (size_t)row * 1024 + col) = (u32)f2b(y1) | ((u32)f2b(y2) << 16);
}

// ---------------- transpose V: (b,s,h,d) -> Vt[(b,h,d), s] ----------------
__global__ __launch_bounds__(256) void transpose_v(const u16* __restrict__ V,
                                                   u16* __restrict__ Vt) {
  __shared__ u16 t[64][65];
  int s0 = blockIdx.x * 64;
  int bh = blockIdx.y;
  int b = bh >> 4, h = bh & 15;
  int tid = threadIdx.x;
  int r = tid >> 2, ch = (tid & 3) * 16;
  const u16* src = V + (size_t)(b * 2048 + s0 + r) * 1024 + h * 64 + ch;
  union { uint4 v[2]; u16 us[16]; } tmp;
  tmp.v[0] = *(const uint4*)src;
  tmp.v[1] = *(const uint4*)(src + 8);
#pragma unroll
  for (int j = 0; j < 16; j++) t[r][ch + j] = tmp.us[j];
  __syncthreads();
  union { uint4 v[2]; u16 us[16]; } o;
#pragma unroll
  for (int j = 0; j < 16; j++) o.us[j] = t[ch + j][r];
  u16* dst = Vt + (size_t)(bh * 64 + r) * 2048 + s0 + ch;
  *(uint4*)dst = o.v[0];
  *(uint4*)(dst + 8) = o.v[1];
}

// ---------------- causal flash attention V4 ----------------
// S^T = K·Q^T (C-layout: k=quad*4+r, q=cc). P C-layout == A-layout of
// mfma_f32_16x16x16_bf16 -> PV straight from registers, no LDS round-trip.
// K/V staged via global_load_lds(16B) into swizzled unpadded LDS (no VGPR
// prefetch buffers). grid: (64 bh, 16 qt), heavy q-tiles first.
__global__ __launch_bounds__(256) void attn_kernel(const u16* __restrict__ Q,
                                                   const u16* __restrict__ K,
                                                   const u16* __restrict__ Vt,
                                                   u16* __restrict__ O) {
  __shared__ u16 Ks[8192];  // 128 keys x 64 d, 8-chunk XOR swizzle  (16 KB)
  __shared__ u16 Vs[8192];  // 64 d x 128 keys, 16-chunk rotate      (16 KB)
#if !HAVE_MFMA16
  __shared__ u16 Ps[4 * 16 * 136];
#endif

  const int bh = blockIdx.x;
  const int qt = 15 - blockIdx.y;  // heavy-first LPT
  const int b = bh >> 4, h = bh & 15;
  const int tid  = threadIdx.x;
  const int lane = tid & 63;
  const int wv   = tid >> 6;
  const int quad = lane >> 4;
  const int cc   = lane & 15;
  const int q0   = qt * 128;

  // Q fragments (B-operand of 16x16x32: B[n=cc][k=quad*8+j]); pre-scaled
  short8 qf[2][2];
#pragma unroll
  for (int mt = 0; mt < 2; mt++) {
    const u16* qp = Q + (size_t)(b * 2048 + q0 + wv * 32 + mt * 16 + cc) * 1024 + h * 64;
    qf[mt][0] = *(const short8*)(qp + quad * 8);
    qf[mt][1] = *(const short8*)(qp + 32 + quad * 8);
  }

  f32x4 o_acc[2][4];
  float m_i[2] = {-3.0e38f, -3.0e38f}, l_i[2] = {0.f, 0.f};
#pragma unroll
  for (int mt = 0; mt < 2; mt++)
#pragma unroll
    for (int nt = 0; nt < 4; nt++) o_acc[mt][nt] = (f32x4){0.f, 0.f, 0.f, 0.f};

  // ---- glds staging addresses ----
  // K: wave wv, instr j covers rows wv*32+j*8 + lane/8; chunk pos=lane&7
  //    holds global chunk g = pos ^ (row&7); row&7 == lane>>3.
  const u16* Kp = K + ((size_t)(b * 2048) + wv * 32 + (lane >> 3)) * 1024 + h * 64 +
                  (((lane & 7) ^ (lane >> 3)) * 8);
  // V: wave wv, instr j covers rows wv*16+j*4 + lane/16; pos=lane&15 holds
  //    global chunk g = (pos - row) & 15  (rotate-by-row swizzle).
  const u16* Vp[4];
#pragma unroll
  for (int j = 0; j < 4; j++) {
    int rl = wv * 16 + j * 4 + (lane >> 4);
    int g  = ((lane & 15) - rl) & 15;
    Vp[j] = Vt + ((size_t)(bh * 64) + rl) * 2048 + g * 8;
  }

  const int nkt = qt + 1;
  const int pk0 = (quad ^ (cc & 7)) * 8;  // Ks chunk offset for g=quad

  for (int kt = 0; kt < nkt; ++kt) {
    __syncthreads();  // all waves done reading previous tile
#pragma unroll
    for (int j = 0; j < 4; j++) {
      glds16(Kp + (size_t)kt * 131072 + j * 8192, Ks + wv * 2048 + j * 512);
      glds16(Vp[j] + kt * 128, Vs + wv * 2048 + j * 512);
    }
    __syncthreads();  // drains vmcnt -> staged tile visible

    const bool diag = (kt == qt);

#pragma unroll
    for (int mt = 0; mt < 2; ++mt) {
      // S^T = K Q^T : rows=keys(quad*4+r), cols=q(cc)
      f32x4 s[8];
#pragma unroll
      for (int nt = 0; nt < 8; ++nt) {
        const int rbase = (nt * 16 + cc) * 64;
        short8 bk0 = *(const short8*)&Ks[rbase + pk0];
        short8 bk1 = *(const short8*)&Ks[rbase + (pk0 ^ 32)];
        f32x4 z = (f32x4){0.f, 0.f, 0.f, 0.f};
        z = __builtin_amdgcn_mfma_f32_16x16x32_bf16(bk0, qf[mt][0], z, 0, 0, 0);
        s[nt] = __builtin_amdgcn_mfma_f32_16x16x32_bf16(bk1, qf[mt][1], z, 0, 0, 0);
      }

      if (diag) {  // uniform branch: mask only on the diagonal tile
        const int qg = q0 + wv * 32 + mt * 16 + cc;
        const int kb = kt * 128 + quad * 4;
#pragma unroll
        for (int nt = 0; nt < 8; ++nt)
#pragma unroll
          for (int r = 0; r < 4; ++r)
            if (kb + nt * 16 + r > qg) s[nt][r] = -3.0e38f;
      }

      float mx = s[0][0];
#pragma unroll
      for (int nt = 0; nt < 8; ++nt)
#pragma unroll
        for (int r = 0; r < 4; ++r) mx = fmaxf(mx, s[nt][r]);
      mx = fmaxf(mx, __shfl_xor(mx, 16));
      mx = fmaxf(mx, __shfl_xor(mx, 32));
      const float mn = fmaxf(m_i[mt], mx);
      const float al = __expf(m_i[mt] - mn);
      m_i[mt] = mn;

      // exp + pack P fragments (A-operand of 16x16x16: m=cc, k=quad*4+j)
      s16x4 pf[8];
      float ps = 0.f;
#pragma unroll
      for (int nt = 0; nt < 8; ++nt) {
        float e0 = __expf(s[nt][0] - mn);
        float e1 = __expf(s[nt][1] - mn);
        float e2 = __expf(s[nt][2] - mn);
        float e3 = __expf(s[nt][3] - mn);
        ps += (e0 + e1) + (e2 + e3);
        union { u32 w[2]; s16x4 v; } pu;
        pu.w[0] = pkbf(e0, e1);
        pu.w[1] = pkbf(e2, e3);
        pf[nt] = pu.v;
      }
      l_i[mt] = l_i[mt] * al + ps;

      // alpha broadcast to o_acc row layout (row q = quad*4+r)
      f32x4 al4;
#pragma unroll
      for (int r = 0; r < 4; ++r) al4[r] = __shfl(al, quad * 4 + r);
#pragma unroll
      for (int nt = 0; nt < 4; ++nt) o_acc[mt][nt] *= al4;

#if HAVE_MFMA16
      // PV: O[q][d] += P[q][k] V[k][d], K=16 per step, P straight from regs
#pragma unroll
      for (int nt = 0; nt < 4; ++nt) {
        const int rv = (nt * 16 + cc) * 128;
#pragma unroll
        for (int kk = 0; kk < 8; ++kk) {
          const int pos = (kk * 2 + (quad >> 1) + cc) & 15;
          s16x4 bv = *(const s16x4*)&Vs[rv + pos * 8 + (quad & 1) * 4];
          o_acc[mt][nt] = MFMA16(pf[kk], bv, o_acc[mt][nt]);
        }
      }
#else
      // fallback: P via per-wave LDS to 16x16x32 A-layout
#pragma unroll
      for (int nt = 0; nt < 8; ++nt) {
        union { s16x4 v; u64 ull; } pu2; pu2.v = pf[nt];
        *(u64*)&Ps[(wv * 16 + cc) * 136 + nt * 16 + quad * 4] = pu2.ull;
      }
      short8 pa[4];
#pragma unroll
      for (int ks = 0; ks < 4; ++ks)
        pa[ks] = *(const short8*)&Ps[(wv * 16 + cc) * 136 + ks * 32 + quad * 8];
#pragma unroll
      for (int nt = 0; nt < 4; ++nt) {
        const int rv = (nt * 16 + cc) * 128;
#pragma unroll
        for (int ks = 0; ks < 4; ++ks) {
          const int pos = (ks * 4 + quad + cc) & 15;
          short8 bv = *(const short8*)&Vs[rv + pos * 8];
          o_acc[mt][nt] = __builtin_amdgcn_mfma_f32_16x16x32_bf16(pa[ks], bv, o_acc[mt][nt], 0, 0, 0);
        }
      }
#endif
    }
  }

  // epilogue: reduce l across quads, broadcast, normalize, store
#pragma unroll
  for (int mt = 0; mt < 2; ++mt) {
    float l = l_i[mt];
    l += __shfl_xor(l, 16);
    l += __shfl_xor(l, 32);
    const float linv = 1.0f / l;
    f32x4 li4;
#pragma unroll
    for (int r = 0; r < 4; ++r) li4[r] = __shfl(linv, quad * 4 + r);
    const int rowb = b * 2048 + q0 + wv * 32 + mt * 16 + quad * 4;
#pragma unroll
    for (int nt = 0; nt < 4; ++nt)
#pragma unroll
      for (int r = 0; r < 4; ++r)
        O[(size_t)(rowb + r) * 1024 + h * 64 + nt * 16 + cc] = f2b(o_acc[mt][nt][r] * li4[r]);
  }
}

// ---------------- launch ----------------
extern "C" void kernel_launch(void* const* d_in, const int* in_sizes, int n_in,
                              void* d_out, int out_size, void* d_ws, size_t ws_size,
                              hipStream_t stream) {
  const float* x  = (const float*)d_in[0];
  const float* wq = (const float*)d_in[1];
  const float* wk = (const float*)d_in[2];
  const float* wv = (const float*)d_in[3];
  const float* wo = (const float*)d_in[4];
  const int* pos  = (const int*)d_in[5];
  float* out = (float*)d_out;

  char* ws = (char*)d_ws;
  // [0,16M): xb -> later Vt   [16M,24M): weights bf16
  // [24M,40M): Q  [40M,56M): K  [56M,72M): V -> later attn_out
  u16* xb  = (u16*)(ws);
  u16* vt  = (u16*)(ws);
  u16* wqb = (u16*)(ws + (16ull << 20));
  u16* wkb = (u16*)(ws + (18ull << 20));
  u16* wvb = (u16*)(ws + (20ull << 20));
  u16* wob = (u16*)(ws + (22ull << 20));
  u16* Qb  = (u16*)(ws + (24ull << 20));
  u16* Kb  = (u16*)(ws + (40ull << 20));
  u16* Vb  = (u16*)(ws + (56ull << 20));
  u16* aO  = Vb;

  cvt_all<<<12288, 256, 0, stream>>>(x, wq, wk, wv, wo, xb, wqb, wkb, wvb, wob);
  gemm_qkv<<<dim3(24, 64), 256, 0, stream>>>(xb, wqb, wkb, wvb, Qb, Kb, Vb);
  rope_kernel<<<dim3(16384, 2), 256, 0, stream>>>(Qb, Kb, pos);
  transpose_v<<<dim3(32, 64), 256, 0, stream>>>(Vb, vt);
  attn_kernel<<<dim3(64, 16), 256, 0, stream>>>(Qb, Kb, vt, aO);
  gemm_out<<<dim3(8, 64), 256, 0, stream>>>(aO, wob, out);
}